// Round 11
// baseline (778.083 us; speedup 1.0000x reference)
//
#include <hip/hip_runtime.h>

typedef unsigned short u16;
typedef __attribute__((ext_vector_type(8))) short short8;
typedef __attribute__((ext_vector_type(4))) float f32x4;

#define NB 32768
#define CHB 8192          // batch chunk (intermediates stay L3-resident)
#define NCH 4

__device__ __forceinline__ u16 f2bf(float x){
  unsigned int u = __float_as_uint(x);
  u += 0x7fffu + ((u >> 16) & 1u);
  return (u16)(u >> 16);
}
__device__ __forceinline__ float bf2f(short h){
  return __uint_as_float(((unsigned int)(u16)h) << 16);
}
__device__ __forceinline__ float lrelu(float v){ return v > 0.f ? v : 0.01f*v; }
__device__ __forceinline__ short8 pack8(float4 a, float4 b){
  short8 p;
  p[0]=(short)f2bf(a.x); p[1]=(short)f2bf(a.y); p[2]=(short)f2bf(a.z); p[3]=(short)f2bf(a.w);
  p[4]=(short)f2bf(b.x); p[5]=(short)f2bf(b.y); p[6]=(short)f2bf(b.z); p[7]=(short)f2bf(b.w);
  return p;
}

// ---------------- K0: weight convert/transpose to bf16 [N][K] ----------------
__global__ __launch_bounds__(256) void k0_conv(
    const float* __restrict__ Wenc, const float* __restrict__ Wsenc,
    const float* __restrict__ Wk, const float* __restrict__ Wsel, const float* __restrict__ Wv,
    const float* __restrict__ Wc1, const float* __restrict__ Wc2,
    u16* __restrict__ WencB, u16* __restrict__ WsencB,
    u16* __restrict__ WkB, u16* __restrict__ WvB, u16* __restrict__ WselB,
    u16* __restrict__ Wc1B, u16* __restrict__ Wc2B)
{
  int idx = blockIdx.x * 256 + threadIdx.x;
  if (idx < 307200){                       // WencB[a][n<128][k<160] = Wenc[a][k][n]
    int a = idx / 20480, r = idx % 20480, n = r / 160, k = r % 160;
    WencB[idx] = f2bf(Wenc[a*20480 + k*128 + n]);
  } else if (idx < 552960){                // WsencB[a][n][k] 128x128
    int i = idx - 307200; int a = i / 16384, r = i % 16384, n = r / 128, k = r % 128;
    WsencB[i] = f2bf(Wsenc[a*16384 + k*128 + n]);
  } else if (idx < 569344){                // WkB[c=nh*32+d][k<128] = Wk[nh][k][d]
    int i = idx - 552960; int c = i / 128, k = i % 128;
    WkB[i] = f2bf(Wk[(c>>5)*4096 + k*32 + (c&31)]);
  } else if (idx < 585728){
    int i = idx - 569344; int c = i / 128, k = i % 128;
    WvB[i] = f2bf(Wv[(c>>5)*4096 + k*32 + (c&31)]);
  } else if (idx < 602112){
    int i = idx - 585728; int c = i / 128, k = i % 128;
    WselB[i] = f2bf(Wsel[(c>>5)*4096 + k*32 + (c&31)]);
  } else if (idx < 1093632){               // Wc1B[a][n<128][k<256] = Wc1[a][k][n]
    int i = idx - 602112; int a = i / 32768, r = i % 32768, n = r / 256, k = r % 256;
    Wc1B[i] = f2bf(Wc1[a*32768 + k*128 + n]);
  } else if (idx < 1155072){               // Wc2B[a][n<32][k<128] = Wc2[a][k][n]
    int i = idx - 1093632; int a = i / 4096, r = i % 4096, n = r / 128, k = r % 128;
    Wc2B[i] = f2bf(Wc2[a*4096 + k*32 + n]);
  }
}

// ---------------- helpers ----------------
__device__ __forceinline__ short8 ldA(const char* lds, int off, int row, int slot){
  return *(const short8*)(lds + off + row*256 + ((slot ^ (row & 7)) << 4));
}
__device__ __forceinline__ void stSwz(char* lds, int off, int row, int col, u16 v){
  *(u16*)(lds + off + row*256 + ((((col>>3) ^ (row&7))) << 4) + ((col&7) << 1)) = v;
}
#define MFMA(a8,b8,c) __builtin_amdgcn_mfma_f32_16x16x32_bf16(a8, b8, c, 0, 0, 0)

// ---------------- K1: encoders + projections (wave-independent, low-reg) ----------------
// grid (CHB/128, 15), 256 thr = 4 waves; wave owns 32 rows (2 row-sets).
// LDS: 8 KB/wave bounce only (32 KB/block). Acc chunked to 4 cols -> 8 live f32x4.
#define K1_LDS 32768

// 2-row-set GEMM, acc-chunked; B direct from global (L2-hot)
__device__ __forceinline__ void gemm2c(
    char* B, const short8* A0, const short8* A1, const u16* __restrict__ W, int ldk,
    const float* __restrict__ bias, bool act, int l15, int l4)
{
  #pragma unroll 1
  for (int cg = 0; cg < 2; ++cg){
    f32x4 a0[4], a1[4];
    #pragma unroll
    for (int cc = 0; cc < 4; ++cc){ a0[cc] = (f32x4)0.f; a1[cc] = (f32x4)0.f; }
    #pragma unroll
    for (int ks = 0; ks < 4; ++ks)
      #pragma unroll
      for (int cc = 0; cc < 4; ++cc){
        int col = cg*64 + cc*16 + l15;
        short8 b8 = *(const short8*)(W + (size_t)col*ldk + ks*32 + l4*8);
        a0[cc] = MFMA(A0[ks], b8, a0[cc]);
        a1[cc] = MFMA(A1[ks], b8, a1[cc]);
      }
    #pragma unroll
    for (int cc = 0; cc < 4; ++cc){
      int col = cg*64 + cc*16 + l15;
      float bb = bias ? bias[col] : 0.0f;
      #pragma unroll
      for (int q = 0; q < 4; ++q){
        float v0 = a0[cc][q] + bb, v1 = a1[cc][q] + bb;
        if (act){ v0 = lrelu(v0); v1 = lrelu(v1); }
        stSwz(B, 0, l4*4 + q,      col, f2bf(v0));
        stSwz(B, 0, 16 + l4*4 + q, col, f2bf(v1));
      }
    }
  }
}
__device__ __forceinline__ void k1_copyout(const char* B, u16* __restrict__ dst,
                                           int a, int m0c, int lane)
{
  #pragma unroll
  for (int it = 0; it < 8; ++it){
    int e = lane + it*64, row = e >> 4, cb = e & 15;
    *(short8*)(dst + ((size_t)a*CHB + m0c + row)*128 + cb*8) =
        *(const short8*)(B + row*256 + ((cb ^ (row&7)) << 4));
  }
}

__global__ __launch_bounds__(256, 4) void k1_enc(
    const float* __restrict__ states, const float* __restrict__ actions, int base,
    const float* __restrict__ benc, const float* __restrict__ bsenc, const float* __restrict__ bvp,
    const u16* __restrict__ WencB, const u16* __restrict__ WsencB,
    const u16* __restrict__ WkB, const u16* __restrict__ WvB, const u16* __restrict__ WselB,
    u16* __restrict__ se_c, u16* __restrict__ keys_c, u16* __restrict__ vals_c, u16* __restrict__ sel_c)
{
  extern __shared__ __align__(16) char lds[];
  const int a = blockIdx.y;
  const int t = threadIdx.x;
  const int w = t >> 6, lane = t & 63;
  const int l15 = lane & 15, l4 = lane >> 4;
  const int m0c = blockIdx.x*128 + w*32;
  const int m0g = base + m0c;
  char* B = lds + w*8192;

  short8 T0[4], T1[4];

  // ---- SE = lrelu(S @ Wsenc + bsenc) ; s scoped to this phase ----
  {
    short8 s0[4], s1[4];
    #pragma unroll
    for (int ks = 0; ks < 4; ++ks){
      const float* p0 = states + ((size_t)a*NB + m0g + l15)*128 + ks*32 + l4*8;
      s0[ks] = pack8(*(const float4*)p0, *(const float4*)(p0 + 4));
      const float* p1 = p0 + 16*128;
      s1[ks] = pack8(*(const float4*)p1, *(const float4*)(p1 + 4));
    }
    gemm2c(B, s0, s1, WsencB + (size_t)a*16384, 128, bsenc + a*128, true, l15, l4);
  }
  k1_copyout(B, se_c, a, m0c, lane);
  #pragma unroll
  for (int ks = 0; ks < 4; ++ks){
    T0[ks] = ldA(B, 0, l15,      ks*4 + l4);   // seA
    T1[ks] = ldA(B, 0, 16 + l15, ks*4 + l4);
  }
  // ---- sel = SE @ Wsel ----
  gemm2c(B, T0, T1, WselB, 128, (const float*)nullptr, false, l15, l4);
  k1_copyout(B, sel_c, a, m0c, lane);

  // ---- SA = lrelu([S|act] @ Wenc + benc) ; s reloaded (L3-hot), scoped ----
  {
    short8 s0[4], s1[4], aa0, aa1;
    #pragma unroll
    for (int ks = 0; ks < 4; ++ks){
      const float* p0 = states + ((size_t)a*NB + m0g + l15)*128 + ks*32 + l4*8;
      s0[ks] = pack8(*(const float4*)p0, *(const float4*)(p0 + 4));
      const float* p1 = p0 + 16*128;
      s1[ks] = pack8(*(const float4*)p1, *(const float4*)(p1 + 4));
    }
    const float* q0 = actions + ((size_t)a*NB + m0g + l15)*32 + l4*8;
    aa0 = pack8(*(const float4*)q0, *(const float4*)(q0 + 4));
    const float* q1 = q0 + 16*32;
    aa1 = pack8(*(const float4*)q1, *(const float4*)(q1 + 4));
    const u16* We = WencB + (size_t)a*20480;
    const float* bi = benc + a*128;
    #pragma unroll 1
    for (int cg = 0; cg < 2; ++cg){
      f32x4 a0[4], a1[4];
      #pragma unroll
      for (int cc = 0; cc < 4; ++cc){ a0[cc] = (f32x4)0.f; a1[cc] = (f32x4)0.f; }
      #pragma unroll
      for (int ks = 0; ks < 4; ++ks)
        #pragma unroll
        for (int cc = 0; cc < 4; ++cc){
          int col = cg*64 + cc*16 + l15;
          short8 b8 = *(const short8*)(We + (size_t)col*160 + ks*32 + l4*8);
          a0[cc] = MFMA(s0[ks], b8, a0[cc]);
          a1[cc] = MFMA(s1[ks], b8, a1[cc]);
        }
      #pragma unroll
      for (int cc = 0; cc < 4; ++cc){
        int col = cg*64 + cc*16 + l15;
        short8 bt = *(const short8*)(We + (size_t)col*160 + 128 + l4*8);
        a0[cc] = MFMA(aa0, bt, a0[cc]);
        a1[cc] = MFMA(aa1, bt, a1[cc]);
        float bb = bi[col];
        #pragma unroll
        for (int q = 0; q < 4; ++q){
          stSwz(B, 0, l4*4 + q,      col, f2bf(lrelu(a0[cc][q] + bb)));
          stSwz(B, 0, 16 + l4*4 + q, col, f2bf(lrelu(a1[cc][q] + bb)));
        }
      }
    }
  }
  #pragma unroll
  for (int ks = 0; ks < 4; ++ks){
    T0[ks] = ldA(B, 0, l15,      ks*4 + l4);   // saA
    T1[ks] = ldA(B, 0, 16 + l15, ks*4 + l4);
  }
  // ---- keys = SA @ Wk ----
  gemm2c(B, T0, T1, WkB, 128, (const float*)nullptr, false, l15, l4);
  k1_copyout(B, keys_c, a, m0c, lane);
  // ---- vals = lrelu(SA @ Wv + bv) ----
  gemm2c(B, T0, T1, WvB, 128, bvp, true, l15, l4);
  k1_copyout(B, vals_c, a, m0c, lane);
}

// ---------------- K2a: pure-VALU exclude-self attention (chunk-local) ----------------
#define KO 0
#define VO 61440
#define K2A_LDS 122880

__global__ __launch_bounds__(1024) void k2a_attn(
    const u16* __restrict__ keys_c, const u16* __restrict__ vals_c,
    const u16* __restrict__ sel_c, u16* __restrict__ attn_c)
{
  extern __shared__ __align__(16) char lds[];
  const int b0 = blockIdx.x * 16;
  const int t = threadIdx.x;
  const int lane = t & 63, w = t >> 6;
  const int b = lane >> 2, h = lane & 3;
  const bool act = w < 15;

  float sf[32];
  size_t base = 0;
  if (act){
    base = ((size_t)w*CHB + b0 + b)*128 + h*32;
    #pragma unroll
    for (int x = 0; x < 4; ++x){
      short8 s8 = *(const short8*)(sel_c + base + x*8);
      #pragma unroll
      for (int y = 0; y < 8; ++y) sf[x*8+y] = bf2f(s8[y]);
    }
  }
  for (int e = t; e < 3840; e += 1024){
    int row = e >> 4, cb = e & 15;
    size_t src = ((size_t)(row >> 4)*CHB + b0 + (row & 15))*128 + cb*8;
    int dst = row*256 + ((cb ^ (row&7)) << 4);
    *(short8*)(lds + KO + dst) = *(const short8*)(keys_c + src);
    *(short8*)(lds + VO + dst) = *(const short8*)(vals_c + src);
  }
  __syncthreads();

  if (act){
    float lg[15];
    #pragma unroll
    for (int j = 0; j < 15; ++j){
      int row = j*16 + b;
      float d = 0.f;
      #pragma unroll
      for (int x = 0; x < 4; ++x){
        short8 k8 = *(const short8*)(lds + KO + row*256 + (((h*4 + x) ^ (row&7)) << 4));
        #pragma unroll
        for (int y = 0; y < 8; ++y) d += bf2f(k8[y]) * sf[x*8+y];
      }
      lg[j] = d * 0.17677669529663687f;
    }
    float mx = -1e30f;
    #pragma unroll
    for (int j = 0; j < 15; ++j) if (j != w) mx = fmaxf(mx, lg[j]);
    float sum = 0.f;
    #pragma unroll
    for (int j = 0; j < 15; ++j){
      float p = (j == w) ? 0.f : __expf(lg[j] - mx);
      lg[j] = p; sum += p;
    }
    float inv = 1.f / sum;
    float oa[32];
    #pragma unroll
    for (int x = 0; x < 32; ++x) oa[x] = 0.f;
    #pragma unroll
    for (int j = 0; j < 15; ++j){
      if (j == w) continue;
      float p = lg[j];
      int row = j*16 + b;
      #pragma unroll
      for (int x = 0; x < 4; ++x){
        short8 v8 = *(const short8*)(lds + VO + row*256 + (((h*4 + x) ^ (row&7)) << 4));
        #pragma unroll
        for (int y = 0; y < 8; ++y) oa[x*8+y] += p * bf2f(v8[y]);
      }
    }
    #pragma unroll
    for (int x = 0; x < 4; ++x){
      short8 o;
      #pragma unroll
      for (int y = 0; y < 8; ++y) o[y] = (short)f2bf(oa[x*8+y] * inv);
      *(short8*)(attn_c + base + x*8) = o;   // aliases keys_c rows this block staged
    }
  }
}

// ---------------- K2b: critic head (wave-independent, chunk-local in, global out) ----------------
__global__ __launch_bounds__(256, 2) void k2b_critic(
    const u16* __restrict__ se_c, const u16* __restrict__ attn_c,
    const u16* __restrict__ Wc1B, const u16* __restrict__ Wc2B,
    const float* __restrict__ bc1, const float* __restrict__ bc2,
    int base, float* __restrict__ outp)
{
  extern __shared__ __align__(16) char lds[];
  const int a = blockIdx.y;
  const int w = threadIdx.x >> 6, lane = threadIdx.x & 63;
  const int l15 = lane & 15, l4 = lane >> 4;
  const int m0c = blockIdx.x*128 + w*32;
  char* B = lds + w*8192;

  short8 se0[4], se1[4], at0[4], at1[4];
  #pragma unroll
  for (int ks = 0; ks < 4; ++ks){
    size_t o0 = ((size_t)a*CHB + m0c + l15)*128 + ks*32 + l4*8;
    size_t o1 = o0 + 16*128;
    se0[ks] = *(const short8*)(se_c + o0);
    se1[ks] = *(const short8*)(se_c + o1);
    at0[ks] = *(const short8*)(attn_c + o0);
    at1[ks] = *(const short8*)(attn_c + o1);
  }
  {
    const u16* Wc = Wc1B + (size_t)a*32768;
    const float* bi = bc1 + a*128;
    #pragma unroll
    for (int c = 0; c < 8; ++c){
      int col = c*16 + l15;
      const u16* Wn = Wc + (size_t)col*256;
      f32x4 a0 = (f32x4)0.f, a1 = (f32x4)0.f;
      #pragma unroll
      for (int ks = 0; ks < 4; ++ks){
        short8 b8 = *(const short8*)(Wn + ks*32 + l4*8);
        a0 = MFMA(se0[ks], b8, a0);
        a1 = MFMA(se1[ks], b8, a1);
      }
      #pragma unroll
      for (int ks = 0; ks < 4; ++ks){
        short8 b8 = *(const short8*)(Wn + 128 + ks*32 + l4*8);
        a0 = MFMA(at0[ks], b8, a0);
        a1 = MFMA(at1[ks], b8, a1);
      }
      float bb = bi[col];
      #pragma unroll
      for (int q = 0; q < 4; ++q){
        stSwz(B, 0, l4*4 + q,      col, f2bf(lrelu(a0[q] + bb)));
        stSwz(B, 0, 16 + l4*4 + q, col, f2bf(lrelu(a1[q] + bb)));
      }
    }
  }
  short8 h0[4], h1[4];
  #pragma unroll
  for (int ks = 0; ks < 4; ++ks){
    h0[ks] = ldA(B, 0, l15,      ks*4 + l4);
    h1[ks] = ldA(B, 0, 16 + l15, ks*4 + l4);
  }
  #pragma unroll
  for (int fn = 0; fn < 2; ++fn){
    int col = fn*16 + l15;
    const u16* Wn = Wc2B + (size_t)a*4096 + (size_t)col*128;
    f32x4 a0 = (f32x4)0.f, a1 = (f32x4)0.f;
    #pragma unroll
    for (int ks = 0; ks < 4; ++ks){
      short8 b8 = *(const short8*)(Wn + ks*32 + l4*8);
      a0 = MFMA(h0[ks], b8, a0);
      a1 = MFMA(h1[ks], b8, a1);
    }
    float bb = bc2[a*32 + col];
    #pragma unroll
    for (int q = 0; q < 4; ++q){
      outp[((size_t)a*NB + base + m0c + l4*4 + q)*32 + col]      = a0[q] + bb;
      outp[((size_t)a*NB + base + m0c + 16 + l4*4 + q)*32 + col] = a1[q] + bb;
    }
  }
}

// ---------------- launch ----------------
extern "C" void kernel_launch(void* const* d_in, const int* in_sizes, int n_in,
                              void* d_out, int out_size, void* d_ws, size_t ws_size,
                              hipStream_t stream)
{
  const float* states  = (const float*)d_in[0];
  const float* actions = (const float*)d_in[1];
  const float* Wenc    = (const float*)d_in[2];
  const float* benc    = (const float*)d_in[3];
  const float* Wsenc   = (const float*)d_in[4];
  const float* bsenc   = (const float*)d_in[5];
  const float* Wk      = (const float*)d_in[6];
  const float* Wsel    = (const float*)d_in[7];
  const float* Wv      = (const float*)d_in[8];
  const float* bv      = (const float*)d_in[9];
  const float* Wc1     = (const float*)d_in[10];
  const float* bc1     = (const float*)d_in[11];
  const float* Wc2     = (const float*)d_in[12];
  const float* bc2     = (const float*)d_in[13];

  char* ws = (char*)d_ws;
  u16* WencB  = (u16*)(ws + 0);
  u16* WsencB = (u16*)(ws + 614400);
  u16* WkB    = (u16*)(ws + 1105920);
  u16* WvB    = (u16*)(ws + 1138688);
  u16* WselB  = (u16*)(ws + 1171456);
  u16* Wc1B   = (u16*)(ws + 1204224);
  u16* Wc2B   = (u16*)(ws + 2187264);
  // chunk-local intermediates: 15*8192*128*2 B = 31457280 each (all four stay L3-resident)
  u16* se_c   = (u16*)(ws + 2310144);
  u16* keys_c = (u16*)(ws + 33767424);   // attn output aliases this
  u16* vals_c = (u16*)(ws + 65224704);
  u16* sel_c  = (u16*)(ws + 96681984);
  if (ws_size < 128139264ULL) return;

  hipFuncSetAttribute((const void*)k1_enc,     hipFuncAttributeMaxDynamicSharedMemorySize, K1_LDS);
  hipFuncSetAttribute((const void*)k2a_attn,   hipFuncAttributeMaxDynamicSharedMemorySize, K2A_LDS);
  hipFuncSetAttribute((const void*)k2b_critic, hipFuncAttributeMaxDynamicSharedMemorySize, 32768);

  k0_conv<<<4512, 256, 0, stream>>>(Wenc, Wsenc, Wk, Wsel, Wv, Wc1, Wc2,
                                    WencB, WsencB, WkB, WvB, WselB, Wc1B, Wc2B);
  for (int ch = 0; ch < NCH; ++ch){
    int base = ch * CHB;
    k1_enc<<<dim3(CHB/128, 15), 256, K1_LDS, stream>>>(states, actions, base,
                                                       benc, bsenc, bv,
                                                       WencB, WsencB, WkB, WvB, WselB,
                                                       se_c, keys_c, vals_c, sel_c);
    k2a_attn<<<CHB/16, 1024, K2A_LDS, stream>>>(keys_c, vals_c, sel_c, keys_c);
    k2b_critic<<<dim3(CHB/128, 15), 256, 32768, stream>>>(se_c, keys_c, Wc1B, Wc2B,
                                                          bc1, bc2, base, (float*)d_out);
  }
}

// Round 12
// 753.451 us; speedup vs baseline: 1.0327x; 1.0327x over previous
//
#include <hip/hip_runtime.h>

typedef unsigned short u16;
typedef __attribute__((ext_vector_type(8))) short short8;
typedef __attribute__((ext_vector_type(4))) float f32x4;

#define NB 32768

__device__ __forceinline__ u16 f2bf(float x){
  unsigned int u = __float_as_uint(x);
  u += 0x7fffu + ((u >> 16) & 1u);
  return (u16)(u >> 16);
}
__device__ __forceinline__ float bf2f(short h){
  return __uint_as_float(((unsigned int)(u16)h) << 16);
}
__device__ __forceinline__ float lrelu(float v){ return v > 0.f ? v : 0.01f*v; }
__device__ __forceinline__ short8 pack8(float4 a, float4 b){
  short8 p;
  p[0]=(short)f2bf(a.x); p[1]=(short)f2bf(a.y); p[2]=(short)f2bf(a.z); p[3]=(short)f2bf(a.w);
  p[4]=(short)f2bf(b.x); p[5]=(short)f2bf(b.y); p[6]=(short)f2bf(b.z); p[7]=(short)f2bf(b.w);
  return p;
}

// ---------------- K0: weight convert/transpose to bf16 [N][K] ----------------
__global__ __launch_bounds__(256) void k0_conv(
    const float* __restrict__ Wenc, const float* __restrict__ Wsenc,
    const float* __restrict__ Wk, const float* __restrict__ Wsel, const float* __restrict__ Wv,
    const float* __restrict__ Wc1, const float* __restrict__ Wc2,
    u16* __restrict__ WencB, u16* __restrict__ WsencB,
    u16* __restrict__ WkB, u16* __restrict__ WvB, u16* __restrict__ WselB,
    u16* __restrict__ Wc1B, u16* __restrict__ Wc2B)
{
  int idx = blockIdx.x * 256 + threadIdx.x;
  if (idx < 307200){                       // WencB[a][n<128][k<160] = Wenc[a][k][n]
    int a = idx / 20480, r = idx % 20480, n = r / 160, k = r % 160;
    WencB[idx] = f2bf(Wenc[a*20480 + k*128 + n]);
  } else if (idx < 552960){                // WsencB[a][n][k] 128x128
    int i = idx - 307200; int a = i / 16384, r = i % 16384, n = r / 128, k = r % 128;
    WsencB[i] = f2bf(Wsenc[a*16384 + k*128 + n]);
  } else if (idx < 569344){                // WkB[c=nh*32+d][k<128] = Wk[nh][k][d]
    int i = idx - 552960; int c = i / 128, k = i % 128;
    WkB[i] = f2bf(Wk[(c>>5)*4096 + k*32 + (c&31)]);
  } else if (idx < 585728){
    int i = idx - 569344; int c = i / 128, k = i % 128;
    WvB[i] = f2bf(Wv[(c>>5)*4096 + k*32 + (c&31)]);
  } else if (idx < 602112){
    int i = idx - 585728; int c = i / 128, k = i % 128;
    WselB[i] = f2bf(Wsel[(c>>5)*4096 + k*32 + (c&31)]);
  } else if (idx < 1093632){               // Wc1B[a][n<128][k<256] = Wc1[a][k][n]
    int i = idx - 602112; int a = i / 32768, r = i % 32768, n = r / 256, k = r % 256;
    Wc1B[i] = f2bf(Wc1[a*32768 + k*128 + n]);
  } else if (idx < 1155072){               // Wc2B[a][n<32][k<128] = Wc2[a][k][n]
    int i = idx - 1093632; int a = i / 4096, r = i % 4096, n = r / 128, k = r % 128;
    Wc2B[i] = f2bf(Wc2[a*4096 + k*32 + n]);
  }
}

// ---------------- helpers ----------------
__device__ __forceinline__ short8 ldA(const char* lds, int off, int row, int slot){
  return *(const short8*)(lds + off + row*256 + ((slot ^ (row & 7)) << 4));
}
__device__ __forceinline__ void stSwz(char* lds, int off, int row, int col, u16 v){
  *(u16*)(lds + off + row*256 + ((((col>>3) ^ (row&7))) << 4) + ((col&7) << 1)) = v;
}
#define MFMA(a8,b8,c) __builtin_amdgcn_mfma_f32_16x16x32_bf16(a8, b8, c, 0, 0, 0)

// ---------------- K1: encoders + projections (wave-independent, low-reg, full batch) ----------------
// grid (256, 15), 256 thr = 4 waves; wave owns 32 rows (2 row-sets).
// LDS: 8 KB/wave bounce (32 KB/block). Acc chunked to 4 cols. (256,4): 128-reg budget, 16 waves/CU.
#define K1_LDS 32768

__device__ __forceinline__ void gemm2c(
    char* B, const short8* A0, const short8* A1, const u16* __restrict__ W, int ldk,
    const float* __restrict__ bias, bool act, int l15, int l4)
{
  #pragma unroll 1
  for (int cg = 0; cg < 2; ++cg){
    f32x4 a0[4], a1[4];
    #pragma unroll
    for (int cc = 0; cc < 4; ++cc){ a0[cc] = (f32x4)0.f; a1[cc] = (f32x4)0.f; }
    #pragma unroll
    for (int ks = 0; ks < 4; ++ks)
      #pragma unroll
      for (int cc = 0; cc < 4; ++cc){
        int col = cg*64 + cc*16 + l15;
        short8 b8 = *(const short8*)(W + (size_t)col*ldk + ks*32 + l4*8);
        a0[cc] = MFMA(A0[ks], b8, a0[cc]);
        a1[cc] = MFMA(A1[ks], b8, a1[cc]);
      }
    #pragma unroll
    for (int cc = 0; cc < 4; ++cc){
      int col = cg*64 + cc*16 + l15;
      float bb = bias ? bias[col] : 0.0f;
      #pragma unroll
      for (int q = 0; q < 4; ++q){
        float v0 = a0[cc][q] + bb, v1 = a1[cc][q] + bb;
        if (act){ v0 = lrelu(v0); v1 = lrelu(v1); }
        stSwz(B, 0, l4*4 + q,      col, f2bf(v0));
        stSwz(B, 0, 16 + l4*4 + q, col, f2bf(v1));
      }
    }
  }
}
__device__ __forceinline__ void k1_copyout(const char* B, u16* __restrict__ dst,
                                           int a, int m0, int lane)
{
  #pragma unroll
  for (int it = 0; it < 8; ++it){
    int e = lane + it*64, row = e >> 4, cb = e & 15;
    *(short8*)(dst + ((size_t)a*NB + m0 + row)*128 + cb*8) =
        *(const short8*)(B + row*256 + ((cb ^ (row&7)) << 4));
  }
}

__global__ __launch_bounds__(256, 4) void k1_enc(
    const float* __restrict__ states, const float* __restrict__ actions,
    const float* __restrict__ benc, const float* __restrict__ bsenc, const float* __restrict__ bvp,
    const u16* __restrict__ WencB, const u16* __restrict__ WsencB,
    const u16* __restrict__ WkB, const u16* __restrict__ WvB, const u16* __restrict__ WselB,
    u16* __restrict__ se_g, u16* __restrict__ keys_g, u16* __restrict__ vals_g, u16* __restrict__ sel_g)
{
  extern __shared__ __align__(16) char lds[];
  const int a = blockIdx.y;
  const int t = threadIdx.x;
  const int w = t >> 6, lane = t & 63;
  const int l15 = lane & 15, l4 = lane >> 4;
  const int m0 = blockIdx.x*128 + w*32;
  char* B = lds + w*8192;

  short8 T0[4], T1[4];

  // ---- SE = lrelu(S @ Wsenc + bsenc) ; s scoped to this phase ----
  {
    short8 s0[4], s1[4];
    #pragma unroll
    for (int ks = 0; ks < 4; ++ks){
      const float* p0 = states + ((size_t)a*NB + m0 + l15)*128 + ks*32 + l4*8;
      s0[ks] = pack8(*(const float4*)p0, *(const float4*)(p0 + 4));
      const float* p1 = p0 + 16*128;
      s1[ks] = pack8(*(const float4*)p1, *(const float4*)(p1 + 4));
    }
    gemm2c(B, s0, s1, WsencB + (size_t)a*16384, 128, bsenc + a*128, true, l15, l4);
  }
  k1_copyout(B, se_g, a, m0, lane);
  #pragma unroll
  for (int ks = 0; ks < 4; ++ks){
    T0[ks] = ldA(B, 0, l15,      ks*4 + l4);   // seA
    T1[ks] = ldA(B, 0, 16 + l15, ks*4 + l4);
  }
  // ---- sel = SE @ Wsel ----
  gemm2c(B, T0, T1, WselB, 128, (const float*)nullptr, false, l15, l4);
  k1_copyout(B, sel_g, a, m0, lane);

  // ---- SA = lrelu([S|act] @ Wenc + benc) ; s reloaded (scoped) ----
  {
    short8 s0[4], s1[4], aa0, aa1;
    #pragma unroll
    for (int ks = 0; ks < 4; ++ks){
      const float* p0 = states + ((size_t)a*NB + m0 + l15)*128 + ks*32 + l4*8;
      s0[ks] = pack8(*(const float4*)p0, *(const float4*)(p0 + 4));
      const float* p1 = p0 + 16*128;
      s1[ks] = pack8(*(const float4*)p1, *(const float4*)(p1 + 4));
    }
    const float* q0 = actions + ((size_t)a*NB + m0 + l15)*32 + l4*8;
    aa0 = pack8(*(const float4*)q0, *(const float4*)(q0 + 4));
    const float* q1 = q0 + 16*32;
    aa1 = pack8(*(const float4*)q1, *(const float4*)(q1 + 4));
    const u16* We = WencB + (size_t)a*20480;
    const float* bi = benc + a*128;
    #pragma unroll 1
    for (int cg = 0; cg < 2; ++cg){
      f32x4 a0[4], a1[4];
      #pragma unroll
      for (int cc = 0; cc < 4; ++cc){ a0[cc] = (f32x4)0.f; a1[cc] = (f32x4)0.f; }
      #pragma unroll
      for (int ks = 0; ks < 4; ++ks)
        #pragma unroll
        for (int cc = 0; cc < 4; ++cc){
          int col = cg*64 + cc*16 + l15;
          short8 b8 = *(const short8*)(We + (size_t)col*160 + ks*32 + l4*8);
          a0[cc] = MFMA(s0[ks], b8, a0[cc]);
          a1[cc] = MFMA(s1[ks], b8, a1[cc]);
        }
      #pragma unroll
      for (int cc = 0; cc < 4; ++cc){
        int col = cg*64 + cc*16 + l15;
        short8 bt = *(const short8*)(We + (size_t)col*160 + 128 + l4*8);
        a0[cc] = MFMA(aa0, bt, a0[cc]);
        a1[cc] = MFMA(aa1, bt, a1[cc]);
        float bb = bi[col];
        #pragma unroll
        for (int q = 0; q < 4; ++q){
          stSwz(B, 0, l4*4 + q,      col, f2bf(lrelu(a0[cc][q] + bb)));
          stSwz(B, 0, 16 + l4*4 + q, col, f2bf(lrelu(a1[cc][q] + bb)));
        }
      }
    }
  }
  #pragma unroll
  for (int ks = 0; ks < 4; ++ks){
    T0[ks] = ldA(B, 0, l15,      ks*4 + l4);   // saA
    T1[ks] = ldA(B, 0, 16 + l15, ks*4 + l4);
  }
  // ---- keys = SA @ Wk ----
  gemm2c(B, T0, T1, WkB, 128, (const float*)nullptr, false, l15, l4);
  k1_copyout(B, keys_g, a, m0, lane);
  // ---- vals = lrelu(SA @ Wv + bv) ----
  gemm2c(B, T0, T1, WvB, 128, bvp, true, l15, l4);
  k1_copyout(B, vals_g, a, m0, lane);
}

// ---------------- K2a: pure-VALU exclude-self attention ----------------
// 2048 blocks x 1024 thr (16 waves). No MFMA -> full arch-VGPR budget.
#define KO 0
#define VO 61440
#define K2A_LDS 122880

__global__ __launch_bounds__(1024) void k2a_attn(
    const u16* __restrict__ keys_g, const u16* __restrict__ vals_g,
    const u16* __restrict__ sel_g, u16* __restrict__ attn_g)
{
  extern __shared__ __align__(16) char lds[];
  const int b0 = blockIdx.x * 16;
  const int t = threadIdx.x;
  const int lane = t & 63, w = t >> 6;
  const int b = lane >> 2, h = lane & 3;
  const bool act = w < 15;

  float sf[32];
  size_t base = 0;
  if (act){
    base = ((size_t)w*NB + b0 + b)*128 + h*32;
    #pragma unroll
    for (int x = 0; x < 4; ++x){
      short8 s8 = *(const short8*)(sel_g + base + x*8);
      #pragma unroll
      for (int y = 0; y < 8; ++y) sf[x*8+y] = bf2f(s8[y]);
    }
  }
  for (int e = t; e < 3840; e += 1024){
    int row = e >> 4, cb = e & 15;
    size_t src = ((size_t)(row >> 4)*NB + b0 + (row & 15))*128 + cb*8;
    int dst = row*256 + ((cb ^ (row&7)) << 4);
    *(short8*)(lds + KO + dst) = *(const short8*)(keys_g + src);
    *(short8*)(lds + VO + dst) = *(const short8*)(vals_g + src);
  }
  __syncthreads();

  if (act){
    float lg[15];
    #pragma unroll
    for (int j = 0; j < 15; ++j){
      int row = j*16 + b;
      float d = 0.f;
      #pragma unroll
      for (int x = 0; x < 4; ++x){
        short8 k8 = *(const short8*)(lds + KO + row*256 + (((h*4 + x) ^ (row&7)) << 4));
        #pragma unroll
        for (int y = 0; y < 8; ++y) d += bf2f(k8[y]) * sf[x*8+y];
      }
      lg[j] = d * 0.17677669529663687f;
    }
    float mx = -1e30f;
    #pragma unroll
    for (int j = 0; j < 15; ++j) if (j != w) mx = fmaxf(mx, lg[j]);
    float sum = 0.f;
    #pragma unroll
    for (int j = 0; j < 15; ++j){
      float p = (j == w) ? 0.f : __expf(lg[j] - mx);
      lg[j] = p; sum += p;
    }
    float inv = 1.f / sum;
    float oa[32];
    #pragma unroll
    for (int x = 0; x < 32; ++x) oa[x] = 0.f;
    #pragma unroll
    for (int j = 0; j < 15; ++j){
      if (j == w) continue;
      float p = lg[j];
      int row = j*16 + b;
      #pragma unroll
      for (int x = 0; x < 4; ++x){
        short8 v8 = *(const short8*)(lds + VO + row*256 + (((h*4 + x) ^ (row&7)) << 4));
        #pragma unroll
        for (int y = 0; y < 8; ++y) oa[x*8+y] += p * bf2f(v8[y]);
      }
    }
    #pragma unroll
    for (int x = 0; x < 4; ++x){
      short8 o;
      #pragma unroll
      for (int y = 0; y < 8; ++y) o[y] = (short)f2bf(oa[x*8+y] * inv);
      *(short8*)(attn_g + base + x*8) = o;
    }
  }
}

// ---------------- K2b: critic head (wave-independent) ----------------
__global__ __launch_bounds__(256, 2) void k2b_critic(
    const u16* __restrict__ se_g, const u16* __restrict__ attn_g,
    const u16* __restrict__ Wc1B, const u16* __restrict__ Wc2B,
    const float* __restrict__ bc1, const float* __restrict__ bc2,
    float* __restrict__ outp)
{
  extern __shared__ __align__(16) char lds[];
  const int a = blockIdx.y;
  const int w = threadIdx.x >> 6, lane = threadIdx.x & 63;
  const int l15 = lane & 15, l4 = lane >> 4;
  const int m0 = blockIdx.x*128 + w*32;
  char* B = lds + w*8192;

  short8 se0[4], se1[4], at0[4], at1[4];
  #pragma unroll
  for (int ks = 0; ks < 4; ++ks){
    size_t o0 = ((size_t)a*NB + m0 + l15)*128 + ks*32 + l4*8;
    size_t o1 = o0 + 16*128;
    se0[ks] = *(const short8*)(se_g + o0);
    se1[ks] = *(const short8*)(se_g + o1);
    at0[ks] = *(const short8*)(attn_g + o0);
    at1[ks] = *(const short8*)(attn_g + o1);
  }
  {
    const u16* Wc = Wc1B + (size_t)a*32768;
    const float* bi = bc1 + a*128;
    #pragma unroll
    for (int c = 0; c < 8; ++c){
      int col = c*16 + l15;
      const u16* Wn = Wc + (size_t)col*256;
      f32x4 a0 = (f32x4)0.f, a1 = (f32x4)0.f;
      #pragma unroll
      for (int ks = 0; ks < 4; ++ks){
        short8 b8 = *(const short8*)(Wn + ks*32 + l4*8);
        a0 = MFMA(se0[ks], b8, a0);
        a1 = MFMA(se1[ks], b8, a1);
      }
      #pragma unroll
      for (int ks = 0; ks < 4; ++ks){
        short8 b8 = *(const short8*)(Wn + 128 + ks*32 + l4*8);
        a0 = MFMA(at0[ks], b8, a0);
        a1 = MFMA(at1[ks], b8, a1);
      }
      float bb = bi[col];
      #pragma unroll
      for (int q = 0; q < 4; ++q){
        stSwz(B, 0, l4*4 + q,      col, f2bf(lrelu(a0[q] + bb)));
        stSwz(B, 0, 16 + l4*4 + q, col, f2bf(lrelu(a1[q] + bb)));
      }
    }
  }
  short8 h0[4], h1[4];
  #pragma unroll
  for (int ks = 0; ks < 4; ++ks){
    h0[ks] = ldA(B, 0, l15,      ks*4 + l4);
    h1[ks] = ldA(B, 0, 16 + l15, ks*4 + l4);
  }
  #pragma unroll
  for (int fn = 0; fn < 2; ++fn){
    int col = fn*16 + l15;
    const u16* Wn = Wc2B + (size_t)a*4096 + (size_t)col*128;
    f32x4 a0 = (f32x4)0.f, a1 = (f32x4)0.f;
    #pragma unroll
    for (int ks = 0; ks < 4; ++ks){
      short8 b8 = *(const short8*)(Wn + ks*32 + l4*8);
      a0 = MFMA(h0[ks], b8, a0);
      a1 = MFMA(h1[ks], b8, a1);
    }
    float bb = bc2[a*32 + col];
    #pragma unroll
    for (int q = 0; q < 4; ++q){
      outp[((size_t)a*NB + m0 + l4*4 + q)*32 + col]      = a0[q] + bb;
      outp[((size_t)a*NB + m0 + 16 + l4*4 + q)*32 + col] = a1[q] + bb;
    }
  }
}

// ---------------- launch ----------------
extern "C" void kernel_launch(void* const* d_in, const int* in_sizes, int n_in,
                              void* d_out, int out_size, void* d_ws, size_t ws_size,
                              hipStream_t stream)
{
  const float* states  = (const float*)d_in[0];
  const float* actions = (const float*)d_in[1];
  const float* Wenc    = (const float*)d_in[2];
  const float* benc    = (const float*)d_in[3];
  const float* Wsenc   = (const float*)d_in[4];
  const float* bsenc   = (const float*)d_in[5];
  const float* Wk      = (const float*)d_in[6];
  const float* Wsel    = (const float*)d_in[7];
  const float* Wv      = (const float*)d_in[8];
  const float* bv      = (const float*)d_in[9];
  const float* Wc1     = (const float*)d_in[10];
  const float* bc1     = (const float*)d_in[11];
  const float* Wc2     = (const float*)d_in[12];
  const float* bc2     = (const float*)d_in[13];

  char* ws = (char*)d_ws;
  u16* WencB  = (u16*)(ws + 0);
  u16* WsencB = (u16*)(ws + 614400);
  u16* WkB    = (u16*)(ws + 1105920);
  u16* WvB    = (u16*)(ws + 1138688);
  u16* WselB  = (u16*)(ws + 1171456);
  u16* Wc1B   = (u16*)(ws + 1204224);
  u16* Wc2B   = (u16*)(ws + 2187264);
  u16* se_g   = (u16*)(ws + 2310144);
  u16* keys_g = (u16*)(ws + 128139264);   // attn output aliases this
  u16* vals_g = (u16*)(ws + 253968384);
  u16* sel_g  = (u16*)(ws + 379797504);
  if (ws_size < 505626624ULL) return;

  hipFuncSetAttribute((const void*)k1_enc,     hipFuncAttributeMaxDynamicSharedMemorySize, K1_LDS);
  hipFuncSetAttribute((const void*)k2a_attn,   hipFuncAttributeMaxDynamicSharedMemorySize, K2A_LDS);
  hipFuncSetAttribute((const void*)k2b_critic, hipFuncAttributeMaxDynamicSharedMemorySize, 32768);

  k0_conv<<<4512, 256, 0, stream>>>(Wenc, Wsenc, Wk, Wsel, Wv, Wc1, Wc2,
                                    WencB, WsencB, WkB, WvB, WselB, Wc1B, Wc2B);
  k1_enc<<<dim3(256, 15), 256, K1_LDS, stream>>>(states, actions, benc, bsenc, bv,
                                                 WencB, WsencB, WkB, WvB, WselB,
                                                 se_g, keys_g, vals_g, sel_g);
  k2a_attn<<<2048, 1024, K2A_LDS, stream>>>(keys_g, vals_g, sel_g, keys_g);
  k2b_critic<<<dim3(256, 15), 256, 32768, stream>>>(se_g, keys_g, Wc1B, Wc2B,
                                                    bc1, bc2, (float*)d_out);
}

// Round 15
// 657.586 us; speedup vs baseline: 1.1832x; 1.1458x over previous
//
#include <hip/hip_runtime.h>

typedef unsigned short u16;
typedef __attribute__((ext_vector_type(8))) short short8;
typedef __attribute__((ext_vector_type(4))) float f32x4;

#define NB 32768

__device__ __forceinline__ u16 f2bf(float x){
  unsigned int u = __float_as_uint(x);
  u += 0x7fffu + ((u >> 16) & 1u);
  return (u16)(u >> 16);
}
__device__ __forceinline__ float bf2f(short h){
  return __uint_as_float(((unsigned int)(u16)h) << 16);
}
__device__ __forceinline__ float lrelu(float v){ return v > 0.f ? v : 0.01f*v; }
__device__ __forceinline__ short8 pack8(float4 a, float4 b){
  short8 p;
  p[0]=(short)f2bf(a.x); p[1]=(short)f2bf(a.y); p[2]=(short)f2bf(a.z); p[3]=(short)f2bf(a.w);
  p[4]=(short)f2bf(b.x); p[5]=(short)f2bf(b.y); p[6]=(short)f2bf(b.z); p[7]=(short)f2bf(b.w);
  return p;
}

// ---------------- K0: weight convert/transpose to bf16 [N][K] ----------------
__global__ __launch_bounds__(256) void k0_conv(
    const float* __restrict__ Wenc, const float* __restrict__ Wsenc,
    const float* __restrict__ Wk, const float* __restrict__ Wsel, const float* __restrict__ Wv,
    const float* __restrict__ Wc1, const float* __restrict__ Wc2,
    u16* __restrict__ WencB, u16* __restrict__ WsencB,
    u16* __restrict__ WkB, u16* __restrict__ WvB, u16* __restrict__ WselB,
    u16* __restrict__ Wc1B, u16* __restrict__ Wc2B)
{
  int idx = blockIdx.x * 256 + threadIdx.x;
  if (idx < 307200){                       // WencB[a][n<128][k<160] = Wenc[a][k][n]
    int a = idx / 20480, r = idx % 20480, n = r / 160, k = r % 160;
    WencB[idx] = f2bf(Wenc[a*20480 + k*128 + n]);
  } else if (idx < 552960){                // WsencB[a][n][k] 128x128
    int i = idx - 307200; int a = i / 16384, r = i % 16384, n = r / 128, k = r % 128;
    WsencB[i] = f2bf(Wsenc[a*16384 + k*128 + n]);
  } else if (idx < 569344){                // WkB[c=nh*32+d][k<128] = Wk[nh][k][d]
    int i = idx - 552960; int c = i / 128, k = i % 128;
    WkB[i] = f2bf(Wk[(c>>5)*4096 + k*32 + (c&31)]);
  } else if (idx < 585728){
    int i = idx - 569344; int c = i / 128, k = i % 128;
    WvB[i] = f2bf(Wv[(c>>5)*4096 + k*32 + (c&31)]);
  } else if (idx < 602112){
    int i = idx - 585728; int c = i / 128, k = i % 128;
    WselB[i] = f2bf(Wsel[(c>>5)*4096 + k*32 + (c&31)]);
  } else if (idx < 1093632){               // Wc1B[a][n<128][k<256] = Wc1[a][k][n]
    int i = idx - 602112; int a = i / 32768, r = i % 32768, n = r / 256, k = r % 256;
    Wc1B[i] = f2bf(Wc1[a*32768 + k*128 + n]);
  } else if (idx < 1155072){               // Wc2B[a][n<32][k<128] = Wc2[a][k][n]
    int i = idx - 1093632; int a = i / 4096, r = i % 4096, n = r / 128, k = r % 128;
    Wc2B[i] = f2bf(Wc2[a*4096 + k*32 + n]);
  }
}

// ---------------- helpers ----------------
__device__ __forceinline__ short8 ldA(const char* lds, int off, int row, int slot){
  return *(const short8*)(lds + off + row*256 + ((slot ^ (row & 7)) << 4));
}
__device__ __forceinline__ void stSwz(char* lds, int off, int row, int col, u16 v){
  *(u16*)(lds + off + row*256 + ((((col>>3) ^ (row&7))) << 4) + ((col&7) << 1)) = v;
}
#define MFMA(a8,b8,c) __builtin_amdgcn_mfma_f32_16x16x32_bf16(a8, b8, c, 0, 0, 0)

// 2-row-set 128x128-K GEMM into per-wave LDS bounce
__device__ __forceinline__ void k1_gemm128(
    char* B, const short8* A0, const short8* A1, const u16* __restrict__ W,
    const float* __restrict__ bias, bool act, int l15, int l4)
{
  #pragma unroll
  for (int c = 0; c < 8; ++c){
    int col = c*16 + l15;
    const u16* Wn = W + (size_t)col*128;
    f32x4 a0 = (f32x4)0.f, a1 = (f32x4)0.f;
    #pragma unroll
    for (int ks = 0; ks < 4; ++ks){
      short8 b8 = *(const short8*)(Wn + ks*32 + l4*8);
      a0 = MFMA(A0[ks], b8, a0);
      a1 = MFMA(A1[ks], b8, a1);
    }
    float bb = bias ? bias[col] : 0.0f;
    #pragma unroll
    for (int q = 0; q < 4; ++q){
      float v0 = a0[q] + bb, v1 = a1[q] + bb;
      if (act){ v0 = lrelu(v0); v1 = lrelu(v1); }
      stSwz(B, 0, l4*4 + q,      col, f2bf(v0));
      stSwz(B, 0, 16 + l4*4 + q, col, f2bf(v1));
    }
  }
}
__device__ __forceinline__ void k1_copyout(const char* B, u16* __restrict__ dst,
                                           int a, int m0, int lane)
{
  #pragma unroll
  for (int it = 0; it < 8; ++it){
    int e = lane + it*64, row = e >> 4, cb = e & 15;
    *(short8*)(dst + ((size_t)a*NB + m0 + row)*128 + cb*8) =
        *(const short8*)(B + row*256 + ((cb ^ (row&7)) << 4));
  }
}

// ---------------- K1: SA/SE encoders + K/V/sel projections (wave-independent) ----------------
// grid (256, 15), 256 thr = 4 waves; wave owns 32 rows. LDS 8 KB/wave bounce. (256,2): 256-reg budget.
// NOTE: (256,3) miscompiles this kernel (rounds 13/14: silent absmax 0.09). Keep (256,2).
__global__ __launch_bounds__(256, 2) void k1_enc(
    const float* __restrict__ states, const float* __restrict__ actions,
    const float* __restrict__ benc, const float* __restrict__ bsenc, const float* __restrict__ bvp,
    const u16* __restrict__ WencB, const u16* __restrict__ WsencB,
    const u16* __restrict__ WkB, const u16* __restrict__ WvB, const u16* __restrict__ WselB,
    u16* __restrict__ se_g, u16* __restrict__ keys_g, u16* __restrict__ vals_g, u16* __restrict__ sel_g)
{
  extern __shared__ __align__(16) char lds[];
  const int a = blockIdx.y;
  const int w = threadIdx.x >> 6, lane = threadIdx.x & 63;
  const int l15 = lane & 15, l4 = lane >> 4;
  const int m0 = blockIdx.x*128 + w*32;
  char* B = lds + w*8192;

  // states/actions A-frags direct from global (two 16-row sets)
  short8 s0[4], s1[4], aa0, aa1;
  #pragma unroll
  for (int ks = 0; ks < 4; ++ks){
    const float* p0 = states + ((size_t)a*NB + m0 + l15)*128 + ks*32 + l4*8;
    s0[ks] = pack8(*(const float4*)p0, *(const float4*)(p0 + 4));
    const float* p1 = p0 + 16*128;
    s1[ks] = pack8(*(const float4*)p1, *(const float4*)(p1 + 4));
  }
  {
    const float* q0 = actions + ((size_t)a*NB + m0 + l15)*32 + l4*8;
    aa0 = pack8(*(const float4*)q0, *(const float4*)(q0 + 4));
    const float* q1 = q0 + 16*32;
    aa1 = pack8(*(const float4*)q1, *(const float4*)(q1 + 4));
  }

  // ---- SE first (bounds liveness): SE = lrelu(S @ Wsenc + bsenc) ----
  k1_gemm128(B, s0, s1, WsencB + (size_t)a*16384, bsenc + a*128, true, l15, l4);
  k1_copyout(B, se_g, a, m0, lane);
  short8 seA0[4], seA1[4];
  #pragma unroll
  for (int ks = 0; ks < 4; ++ks){
    seA0[ks] = ldA(B, 0, l15,      ks*4 + l4);
    seA1[ks] = ldA(B, 0, 16 + l15, ks*4 + l4);
  }

  // ---- SA = lrelu([S|act] @ Wenc + benc) -> bounce only (not written to global) ----
  {
    const u16* We = WencB + (size_t)a*20480;
    const float* bi = benc + a*128;
    #pragma unroll
    for (int c = 0; c < 8; ++c){
      int col = c*16 + l15;
      const u16* Wn = We + (size_t)col*160;
      f32x4 a0 = (f32x4)0.f, a1 = (f32x4)0.f;
      #pragma unroll
      for (int ks = 0; ks < 4; ++ks){
        short8 b8 = *(const short8*)(Wn + ks*32 + l4*8);
        a0 = MFMA(s0[ks], b8, a0);
        a1 = MFMA(s1[ks], b8, a1);
      }
      short8 bt = *(const short8*)(Wn + 128 + l4*8);
      a0 = MFMA(aa0, bt, a0);
      a1 = MFMA(aa1, bt, a1);
      float bb = bi[col];
      #pragma unroll
      for (int q = 0; q < 4; ++q){
        float v0 = a0[q] + bb, v1 = a1[q] + bb;
        v0 = lrelu(v0); v1 = lrelu(v1);
        stSwz(B, 0, l4*4 + q,      col, f2bf(v0));
        stSwz(B, 0, 16 + l4*4 + q, col, f2bf(v1));
      }
    }
  }
  short8 saA0[4], saA1[4];
  #pragma unroll
  for (int ks = 0; ks < 4; ++ks){
    saA0[ks] = ldA(B, 0, l15,      ks*4 + l4);
    saA1[ks] = ldA(B, 0, 16 + l15, ks*4 + l4);
  }

  // ---- keys = SA @ Wk ----
  k1_gemm128(B, saA0, saA1, WkB, (const float*)nullptr, false, l15, l4);
  k1_copyout(B, keys_g, a, m0, lane);
  // ---- vals = lrelu(SA @ Wv + bv) ----
  k1_gemm128(B, saA0, saA1, WvB, bvp, true, l15, l4);
  k1_copyout(B, vals_g, a, m0, lane);
  // ---- sel = SE @ Wsel ----
  k1_gemm128(B, seA0, seA1, WselB, (const float*)nullptr, false, l15, l4);
  k1_copyout(B, sel_g, a, m0, lane);
}

// ---------------- K2a: pure-VALU exclude-self attention ----------------
// 2048 blocks x 1024 thr (16 waves). No MFMA -> full arch-VGPR budget.
// LDS: K @0 [240][256B swz], V @61440. attn output aliases keys_g.
#define KO 0
#define VO 61440
#define K2A_LDS 122880

__global__ __launch_bounds__(1024) void k2a_attn(
    const u16* __restrict__ keys_g, const u16* __restrict__ vals_g,
    const u16* __restrict__ sel_g, u16* __restrict__ attn_g)
{
  extern __shared__ __align__(16) char lds[];
  const int b0 = blockIdx.x * 16;
  const int t = threadIdx.x;
  const int lane = t & 63, w = t >> 6;
  const int b = lane >> 2, h = lane & 3;
  const bool act = w < 15;

  float sf[32];
  size_t base = 0;
  if (act){
    base = ((size_t)w*NB + b0 + b)*128 + h*32;
    #pragma unroll
    for (int x = 0; x < 4; ++x){
      short8 s8 = *(const short8*)(sel_g + base + x*8);
      #pragma unroll
      for (int y = 0; y < 8; ++y) sf[x*8+y] = bf2f(s8[y]);
    }
  }
  for (int e = t; e < 3840; e += 1024){
    int row = e >> 4, cb = e & 15;
    size_t src = ((size_t)(row >> 4)*NB + b0 + (row & 15))*128 + cb*8;
    int dst = row*256 + ((cb ^ (row&7)) << 4);
    *(short8*)(lds + KO + dst) = *(const short8*)(keys_g + src);
    *(short8*)(lds + VO + dst) = *(const short8*)(vals_g + src);
  }
  __syncthreads();

  if (act){
    float lg[15];
    #pragma unroll
    for (int j = 0; j < 15; ++j){
      int row = j*16 + b;
      float d = 0.f;
      #pragma unroll
      for (int x = 0; x < 4; ++x){
        short8 k8 = *(const short8*)(lds + KO + row*256 + (((h*4 + x) ^ (row&7)) << 4));
        #pragma unroll
        for (int y = 0; y < 8; ++y) d += bf2f(k8[y]) * sf[x*8+y];
      }
      lg[j] = d * 0.17677669529663687f;        // 1/sqrt(32)
    }
    float mx = -1e30f;
    #pragma unroll
    for (int j = 0; j < 15; ++j) if (j != w) mx = fmaxf(mx, lg[j]);
    float sum = 0.f;
    #pragma unroll
    for (int j = 0; j < 15; ++j){
      float p = (j == w) ? 0.f : __expf(lg[j] - mx);
      lg[j] = p; sum += p;
    }
    float inv = 1.f / sum;
    float oa[32];
    #pragma unroll
    for (int x = 0; x < 32; ++x) oa[x] = 0.f;
    #pragma unroll
    for (int j = 0; j < 15; ++j){
      if (j == w) continue;
      float p = lg[j];
      int row = j*16 + b;
      #pragma unroll
      for (int x = 0; x < 4; ++x){
        short8 v8 = *(const short8*)(lds + VO + row*256 + (((h*4 + x) ^ (row&7)) << 4));
        #pragma unroll
        for (int y = 0; y < 8; ++y) oa[x*8+y] += p * bf2f(v8[y]);
      }
    }
    #pragma unroll
    for (int x = 0; x < 4; ++x){
      short8 o;
      #pragma unroll
      for (int y = 0; y < 8; ++y) o[y] = (short)f2bf(oa[x*8+y] * inv);
      *(short8*)(attn_g + base + x*8) = o;
    }
  }
}

// ---------------- K2b: critic head (wave-independent) ----------------
__global__ __launch_bounds__(256, 2) void k2b_critic(
    const u16* __restrict__ se_g, const u16* __restrict__ attn_g,
    const u16* __restrict__ Wc1B, const u16* __restrict__ Wc2B,
    const float* __restrict__ bc1, const float* __restrict__ bc2,
    float* __restrict__ outp)
{
  extern __shared__ __align__(16) char lds[];
  const int a = blockIdx.y;
  const int w = threadIdx.x >> 6, lane = threadIdx.x & 63;
  const int l15 = lane & 15, l4 = lane >> 4;
  const int m0 = blockIdx.x*128 + w*32;
  char* B = lds + w*8192;

  short8 se0[4], se1[4], at0[4], at1[4];
  #pragma unroll
  for (int ks = 0; ks < 4; ++ks){
    size_t o0 = ((size_t)a*NB + m0 + l15)*128 + ks*32 + l4*8;
    size_t o1 = o0 + 16*128;
    se0[ks] = *(const short8*)(se_g + o0);
    se1[ks] = *(const short8*)(se_g + o1);
    at0[ks] = *(const short8*)(attn_g + o0);
    at1[ks] = *(const short8*)(attn_g + o1);
  }
  // hidden = lrelu([se|attn] @ Wc1 + bc1) -> bounce
  {
    const u16* Wc = Wc1B + (size_t)a*32768;
    const float* bi = bc1 + a*128;
    #pragma unroll
    for (int c = 0; c < 8; ++c){
      int col = c*16 + l15;
      const u16* Wn = Wc + (size_t)col*256;
      f32x4 a0 = (f32x4)0.f, a1 = (f32x4)0.f;
      #pragma unroll
      for (int ks = 0; ks < 4; ++ks){
        short8 b8 = *(const short8*)(Wn + ks*32 + l4*8);
        a0 = MFMA(se0[ks], b8, a0);
        a1 = MFMA(se1[ks], b8, a1);
      }
      #pragma unroll
      for (int ks = 0; ks < 4; ++ks){
        short8 b8 = *(const short8*)(Wn + 128 + ks*32 + l4*8);
        a0 = MFMA(at0[ks], b8, a0);
        a1 = MFMA(at1[ks], b8, a1);
      }
      float bb = bi[col];
      #pragma unroll
      for (int q = 0; q < 4; ++q){
        float v0 = a0[q] + bb, v1 = a1[q] + bb;
        v0 = lrelu(v0); v1 = lrelu(v1);
        stSwz(B, 0, l4*4 + q,      col, f2bf(v0));
        stSwz(B, 0, 16 + l4*4 + q, col, f2bf(v1));
      }
    }
  }
  // out = hidden @ Wc2 + bc2
  short8 h0[4], h1[4];
  #pragma unroll
  for (int ks = 0; ks < 4; ++ks){
    h0[ks] = ldA(B, 0, l15,      ks*4 + l4);
    h1[ks] = ldA(B, 0, 16 + l15, ks*4 + l4);
  }
  #pragma unroll
  for (int fn = 0; fn < 2; ++fn){
    int col = fn*16 + l15;
    const u16* Wn = Wc2B + (size_t)a*4096 + (size_t)col*128;
    f32x4 a0 = (f32x4)0.f, a1 = (f32x4)0.f;
    #pragma unroll
    for (int ks = 0; ks < 4; ++ks){
      short8 b8 = *(const short8*)(Wn + ks*32 + l4*8);
      a0 = MFMA(h0[ks], b8, a0);
      a1 = MFMA(h1[ks], b8, a1);
    }
    float bb = bc2[a*32 + col];
    #pragma unroll
    for (int q = 0; q < 4; ++q){
      outp[((size_t)a*NB + m0 + l4*4 + q)*32 + col]      = a0[q] + bb;
      outp[((size_t)a*NB + m0 + 16 + l4*4 + q)*32 + col] = a1[q] + bb;
    }
  }
}

// ---------------- launch ----------------
extern "C" void kernel_launch(void* const* d_in, const int* in_sizes, int n_in,
                              void* d_out, int out_size, void* d_ws, size_t ws_size,
                              hipStream_t stream)
{
  const float* states  = (const float*)d_in[0];
  const float* actions = (const float*)d_in[1];
  const float* Wenc    = (const float*)d_in[2];
  const float* benc    = (const float*)d_in[3];
  const float* Wsenc   = (const float*)d_in[4];
  const float* bsenc   = (const float*)d_in[5];
  const float* Wk      = (const float*)d_in[6];
  const float* Wsel    = (const float*)d_in[7];
  const float* Wv      = (const float*)d_in[8];
  const float* bv      = (const float*)d_in[9];
  const float* Wc1     = (const float*)d_in[10];
  const float* bc1     = (const float*)d_in[11];
  const float* Wc2     = (const float*)d_in[12];
  const float* bc2     = (const float*)d_in[13];

  char* ws = (char*)d_ws;
  u16* WencB  = (u16*)(ws + 0);
  u16* WsencB = (u16*)(ws + 614400);
  u16* WkB    = (u16*)(ws + 1105920);
  u16* WvB    = (u16*)(ws + 1138688);
  u16* WselB  = (u16*)(ws + 1171456);
  u16* Wc1B   = (u16*)(ws + 1204224);
  u16* Wc2B   = (u16*)(ws + 2187264);
  u16* se_g   = (u16*)(ws + 2310144);
  u16* keys_g = (u16*)(ws + 128139264);   // attn output aliases this
  u16* vals_g = (u16*)(ws + 253968384);
  u16* sel_g  = (u16*)(ws + 379797504);
  if (ws_size < 505626624ULL) return;

  hipFuncSetAttribute((const void*)k1_enc,     hipFuncAttributeMaxDynamicSharedMemorySize, 32768);
  hipFuncSetAttribute((const void*)k2a_attn,   hipFuncAttributeMaxDynamicSharedMemorySize, K2A_LDS);
  hipFuncSetAttribute((const void*)k2b_critic, hipFuncAttributeMaxDynamicSharedMemorySize, 32768);

  k0_conv<<<4512, 256, 0, stream>>>(Wenc, Wsenc, Wk, Wsel, Wv, Wc1, Wc2,
                                    WencB, WsencB, WkB, WvB, WselB, Wc1B, Wc2B);
  k1_enc<<<dim3(256, 15), 256, 32768, stream>>>(states, actions, benc, bsenc, bv,
                                                WencB, WsencB, WkB, WvB, WselB,
                                                se_g, keys_g, vals_g, sel_g);
  k2a_attn<<<2048, 1024, K2A_LDS, stream>>>(keys_g, vals_g, sel_g, keys_g);
  k2b_critic<<<dim3(256, 15), 256, 32768, stream>>>(se_g, keys_g, Wc1B, Wc2B,
                                                    bc1, bc2, (float*)d_out);
}